// Round 11
// baseline (374.721 us; speedup 1.0000x reference)
//
#include <hip/hip_runtime.h>
#include <hip/hip_bf16.h>
#include <stdint.h>

#define BATCH 4096
#define N_TOT 8192
#define D_DIM 256
#define SHIFT 150.0f
#define SQRT2 1.41421356237309515f
#define NBLK 528            // 32*33/2 triangular 256x256 tiles

typedef __bf16 bf16_t;
typedef bf16_t bf16x8 __attribute__((ext_vector_type(8)));
typedef bf16_t bf16x4 __attribute__((ext_vector_type(4)));
typedef float f32x4 __attribute__((ext_vector_type(4)));

// global -> LDS direct copy, 16B per lane. LDS dest is wave-uniform base;
// HW scatters lane*16B linearly (cannot swizzle the dest -> swizzle the src).
__device__ __forceinline__ void gl_lds16(const void* g, void* l) {
  __builtin_amdgcn_global_load_lds(
      (const __attribute__((address_space(1))) void*)(uintptr_t)g,
      (__attribute__((address_space(3))) void*)(uint32_t)(uintptr_t)l,
      16, 0, 0);
}

// Fused: bf16 convert (x sqrt2), positive-pair dot partials, Zrow zero-init.
// Row-major hb layout (r9-verified). 1024 blocks x 256 threads.
__global__ void k_prep(const float* __restrict__ hi, const float* __restrict__ hj,
                       bf16_t* __restrict__ hb, float* __restrict__ Zrow,
                       float* __restrict__ posPartial) {
  const int wave = threadIdx.x >> 6, lane = threadIdx.x & 63;
  const int r = blockIdx.x * 4 + wave;
  const size_t off = (size_t)r * D_DIM + lane * 4;
  float4 a = *(const float4*)(hi + off);
  float4 b = *(const float4*)(hj + off);

  bf16x4 oa, ob;
  oa[0] = (bf16_t)(a.x * SQRT2); oa[1] = (bf16_t)(a.y * SQRT2);
  oa[2] = (bf16_t)(a.z * SQRT2); oa[3] = (bf16_t)(a.w * SQRT2);
  ob[0] = (bf16_t)(b.x * SQRT2); ob[1] = (bf16_t)(b.y * SQRT2);
  ob[2] = (bf16_t)(b.z * SQRT2); ob[3] = (bf16_t)(b.w * SQRT2);
  *(bf16x4*)(hb + off) = oa;
  *(bf16x4*)(hb + (size_t)BATCH * D_DIM + off) = ob;

  float d = a.x * b.x + a.y * b.y + a.z * b.z + a.w * b.w;
#pragma unroll
  for (int o = 32; o >= 1; o >>= 1) d += __shfl_xor(d, o);
  __shared__ float ps[4];
  if (lane == 0) ps[wave] = d;
  // zero 8 Zrow entries per block (8192 total over 1024 blocks)
  if (threadIdx.x < 8) Zrow[blockIdx.x * 8 + threadIdx.x] = 0.f;
  __syncthreads();
  if (threadIdx.x == 0) posPartial[blockIdx.x] = ps[0] + ps[1] + ps[2] + ps[3];
}

// Upper-triangular 256x256 tiles of sim = hb.hb^T; fused exp(sim-SHIFT) with
// row/col sum accumulation into Zrow. 528 blocks, 8 waves.
// WHY 256^2: cross-round model -- effective L2->CU BW for this pattern is
// ~13 TB/s, so the GEMM stage is TRAFFIC-bound: 128^2 tile = 266MB = ~20us
// floor (r9 hit 38.5); 256^2 = 138MB = ~11us floor. r7 ran this geometry at
// 47us with two defects, both fixed here:
//  (a) swizzle key was (r&3): rows 0,4,8,12 collided -> 1.62M bank conflicts.
//      Correct key for 64B rows is ((r>>1)&3) -- r9-validated.
//  (b) __launch_bounds__(512,2) = 1 block/CU (2nd arg is waves/EU; for 512-thr
//      blocks, 2 blocks/CU needs 4). Now (512,4): 16 waves/CU TLP, VGPR<=128.
// Counted-vmcnt dbuf skeleton (r6/r9-verified): per slab STAGE(next,4x
// gl_lds16) -> vmcnt(4) -> s_barrier -> 12x ds_read_b128 -> lgkmcnt(0)+
// sched_barrier(0) -> 32 MFMA -> s_barrier. No vmcnt(0) inside the loop.
__global__ __launch_bounds__(512, 4) void k_gemm(const bf16_t* __restrict__ hb,
                                                 float* __restrict__ Zrow) {
  // decode linear block id -> (bi <= bj) triangular pair
  const int t = blockIdx.x;
  int bj = (int)((sqrtf(8.0f * (float)t + 1.0f) - 1.0f) * 0.5f);
  while ((bj + 1) * (bj + 2) / 2 <= t) ++bj;
  while (bj * (bj + 1) / 2 > t) --bj;
  const int bi = t - bj * (bj + 1) / 2;
  const int rBase = bi * 256;
  const int cBase = bj * 256;
  const bool diag = (bi == bj);

  // [2 buffers][256 rows][32 K] bf16 = 16 KB per buffer per matrix; 64 KB.
  __shared__ __align__(16) bf16_t As[2][256][32];
  __shared__ __align__(16) bf16_t Bs[2][256][32];
  const int tid = threadIdx.x;
  const int lane = tid & 63;
  const int wave = tid >> 6;  // 0..7

  // ---- staging: waves 0-3 -> As 64-row quarters; 4-7 -> Bs quarters -----
  // LDS dest linear: lane -> row = lane>>2, chunk = lane&3 (16 rows/issue).
  // Source chunk pre-swizzled with key (row>>1)&3 = (lane>>3)&3.
  const int sq = wave & 3;
  const size_t stageRow = (size_t)((wave < 4 ? rBase : cBase) + sq * 64);
  const int schunk = (lane & 3) ^ ((lane >> 3) & 3);
  const bf16_t* gsrc = hb + (stageRow + (lane >> 2)) * D_DIM + schunk * 8;
  bf16_t* lbase = (wave < 4) ? &As[0][sq * 64][0] : &Bs[0][sq * 64][0];

  // stage slab s (32 K-cols, 64 rows/wave) into buffer b: 4 x gl_lds16.
  auto STAGE = [&](int s, int b) {
#pragma unroll
    for (int i = 0; i < 4; ++i)
      gl_lds16(gsrc + (size_t)(i * 16) * D_DIM + s * 32,
               lbase + b * (256 * 32) + i * 16 * 32);
  };

  // ---- fragment geometry: wave grid 4(row strips of 64) x 2(col 128) ----
  const int wm = wave >> 1, wn = wave & 1;
  const int quad = lane >> 4, l16 = lane & 15;
  // read-side un-swizzle: row = base16 + l16 -> key ((l16>>1)&3); uniform
  // 2-way bank aliasing = free (m136).
  const int cc = (quad ^ ((l16 >> 1) & 3)) * 8;

  f32x4 acc[4][8];
#pragma unroll
  for (int i = 0; i < 4; ++i)
#pragma unroll
    for (int j = 0; j < 8; ++j) acc[i][j] = (f32x4){0.f, 0.f, 0.f, 0.f};

  STAGE(0, 0);  // prologue: slab 0 in flight

#pragma unroll
  for (int k = 0; k < 8; ++k) {
    const int b = k & 1;
    if (k + 1 < 8) {
      STAGE(k + 1, b ^ 1);  // next slab's loads fly across the barrier
      asm volatile("s_waitcnt vmcnt(4)" ::: "memory");  // slab k landed
    } else {
      asm volatile("s_waitcnt vmcnt(0)" ::: "memory");  // last slab: drain
    }
    __builtin_amdgcn_s_barrier();  // bar1: slab k fully visible in LDS

    bf16x8 af[4], bfr[8];
#pragma unroll
    for (int mt = 0; mt < 4; ++mt)
      af[mt] = *(const bf16x8*)&As[b][wm * 64 + mt * 16 + l16][cc];
#pragma unroll
    for (int nt = 0; nt < 8; ++nt)
      bfr[nt] = *(const bf16x8*)&Bs[b][wn * 128 + nt * 16 + l16][cc];
    asm volatile("s_waitcnt lgkmcnt(0)" ::: "memory");  // reads in registers
    __builtin_amdgcn_sched_barrier(0);                  // rule #18 fence

#pragma unroll
    for (int mt = 0; mt < 4; ++mt)
#pragma unroll
      for (int nt = 0; nt < 8; ++nt)
        acc[mt][nt] = __builtin_amdgcn_mfma_f32_16x16x32_bf16(
            af[mt], bfr[nt], acc[mt][nt], 0, 0, 0);

    __builtin_amdgcn_s_barrier();  // bar2: buffer b free for overwrite
  }

  // epilogue: e = exp(sim - SHIFT); row sums always, col sums for off-diag
  // (symmetry: entry (r,c) also stands in for (c,r)). r7-verified numerics.
  const int rW = rBase + wm * 64 + quad * 4;
  const int cW = cBase + wn * 128 + l16;
  float colAcc[8] = {0.f, 0.f, 0.f, 0.f, 0.f, 0.f, 0.f, 0.f};
#pragma unroll
  for (int mt = 0; mt < 4; ++mt) {
#pragma unroll
    for (int rg = 0; rg < 4; ++rg) {
      const int rr = rW + mt * 16 + rg;
      float s = 0.f;
#pragma unroll
      for (int nt = 0; nt < 8; ++nt) {
        float e = __expf(acc[mt][nt][rg] - SHIFT);
        if (diag && (rr == cW + nt * 16)) e = 0.f;  // mask self-similarity
        s += e;
        colAcc[nt] += e;
      }
      s += __shfl_xor(s, 1);
      s += __shfl_xor(s, 2);
      s += __shfl_xor(s, 4);
      s += __shfl_xor(s, 8);
      if (l16 == 0) atomicAdd(&Zrow[rr], s);
    }
  }
  if (!diag) {
#pragma unroll
    for (int nt = 0; nt < 8; ++nt) {
      float c = colAcc[nt];
      c += __shfl_xor(c, 16);
      c += __shfl_xor(c, 32);
      if (lane < 16) atomicAdd(&Zrow[cW + nt * 16], c);
    }
  }
}

// One block: loss = mean(log Z + SHIFT) - sum(dot)/2048
__global__ void k_finish(const float* __restrict__ Zrow,
                         const float* __restrict__ posPartial,
                         float* __restrict__ out) {
  const int t = threadIdx.x;  // 0..1023
  float4 z0 = *(const float4*)(Zrow + t * 8);
  float4 z1 = *(const float4*)(Zrow + t * 8 + 4);
  float sl = __logf(z0.x) + __logf(z0.y) + __logf(z0.z) + __logf(z0.w) +
             __logf(z1.x) + __logf(z1.y) + __logf(z1.z) + __logf(z1.w);
  float sp = posPartial[t];
#pragma unroll
  for (int o = 32; o >= 1; o >>= 1) {
    sl += __shfl_xor(sl, o);
    sp += __shfl_xor(sp, o);
  }
  __shared__ float pl[16], pp[16];
  const int wave = t >> 6, lane = t & 63;
  if (lane == 0) { pl[wave] = sl; pp[wave] = sp; }
  __syncthreads();
  if (t == 0) {
    float L = 0.f, P = 0.f;
    for (int i = 0; i < 16; ++i) { L += pl[i]; P += pp[i]; }
    out[0] = L / (float)N_TOT + SHIFT - P / 2048.0f;
  }
}

extern "C" void kernel_launch(void* const* d_in, const int* in_sizes, int n_in,
                              void* d_out, int out_size, void* d_ws, size_t ws_size,
                              hipStream_t stream) {
  const float* hi = (const float*)d_in[0];
  const float* hj = (const float*)d_in[1];
  float* out = (float*)d_out;

  bf16_t* hb = (bf16_t*)d_ws;                                        // 4 MB
  float* Zrow = (float*)((char*)d_ws + (size_t)N_TOT * D_DIM * 2);   // 32 KB
  float* posPartial = Zrow + N_TOT;                                  // 4 KB

  k_prep<<<1024, 256, 0, stream>>>(hi, hj, hb, Zrow, posPartial);
  k_gemm<<<NBLK, 512, 0, stream>>>(hb, Zrow);
  k_finish<<<1, 1024, 0, stream>>>(Zrow, posPartial, out);
}

// Round 12
// 141.720 us; speedup vs baseline: 2.6441x; 2.6441x over previous
//
#include <hip/hip_runtime.h>
#include <hip/hip_bf16.h>
#include <stdint.h>

#define BATCH 4096
#define N_TOT 8192
#define D_DIM 256
#define SHIFT 150.0f
#define SQRT2 1.41421356237309515f
#define NBLK 2080  // 64*65/2 triangular 128x128 tiles

typedef __bf16 bf16_t;
typedef bf16_t bf16x8 __attribute__((ext_vector_type(8)));
typedef bf16_t bf16x4 __attribute__((ext_vector_type(4)));
typedef float f32x4 __attribute__((ext_vector_type(4)));

// global -> LDS direct copy, 16B per lane. LDS dest is wave-uniform base;
// HW scatters lane*16B linearly (cannot swizzle the dest -> swizzle the src).
__device__ __forceinline__ void gl_lds16(const void* g, void* l) {
  __builtin_amdgcn_global_load_lds(
      (const __attribute__((address_space(1))) void*)(uintptr_t)g,
      (__attribute__((address_space(3))) void*)(uint32_t)(uintptr_t)l,
      16, 0, 0);
}

// Fused: bf16 convert (x sqrt2), positive-pair dot partials, Zrow+ticket init.
// 1024 blocks x 256 threads; wave w of block b owns row r = b*4+w.
__global__ void k_prep(const float* __restrict__ hi, const float* __restrict__ hj,
                       bf16_t* __restrict__ hb, float* __restrict__ Zrow,
                       float* __restrict__ posPartial, unsigned* __restrict__ ticket) {
  const int wave = threadIdx.x >> 6, lane = threadIdx.x & 63;
  const int r = blockIdx.x * 4 + wave;
  const size_t off = (size_t)r * D_DIM + lane * 4;
  float4 a = *(const float4*)(hi + off);
  float4 b = *(const float4*)(hj + off);

  bf16x4 oa, ob;
  oa[0] = (bf16_t)(a.x * SQRT2); oa[1] = (bf16_t)(a.y * SQRT2);
  oa[2] = (bf16_t)(a.z * SQRT2); oa[3] = (bf16_t)(a.w * SQRT2);
  ob[0] = (bf16_t)(b.x * SQRT2); ob[1] = (bf16_t)(b.y * SQRT2);
  ob[2] = (bf16_t)(b.z * SQRT2); ob[3] = (bf16_t)(b.w * SQRT2);
  *(bf16x4*)(hb + off) = oa;
  *(bf16x4*)(hb + (size_t)BATCH * D_DIM + off) = ob;

  float d = a.x * b.x + a.y * b.y + a.z * b.z + a.w * b.w;
#pragma unroll
  for (int o = 32; o >= 1; o >>= 1) d += __shfl_xor(d, o);
  __shared__ float ps[4];
  if (lane == 0) ps[wave] = d;
  // zero 8 Zrow entries per block (8192 total over 1024 blocks) + ticket
  if (threadIdx.x < 8) Zrow[blockIdx.x * 8 + threadIdx.x] = 0.f;
  if (blockIdx.x == 0 && threadIdx.x == 8) *ticket = 0u;
  __syncthreads();
  if (threadIdx.x == 0) posPartial[blockIdx.x] = ps[0] + ps[1] + ps[2] + ps[3];
}

// Upper-triangular 128x128 tiles of sim = hb.hb^T; fused exp(sim-SHIFT) with
// row/col sum accumulation into Zrow. 2080 blocks, 4 waves, 4 blocks/CU.
// r9 (best, 38.5us) geometry with ONE barrier per slab instead of two:
//   per slab k: STAGE(k+1 -> b^1) ; ds_read(b) ; lgkmcnt(0)+sched_barrier ;
//               16 MFMA ; vmcnt(0) ; s_barrier
// Safety: wave Y's reads of buf b retire at its lgkmcnt(0) BEFORE it reaches
// bar(k); wave X issues STAGE(k+2 -> b) only AFTER bar(k) -> no WAR race.
// vmcnt(0) waits only on STAGE(k+1), issued ~600cyc earlier under compute
// cover (T3-minimum 2-phase, ~92% of 8-phase per the catalog).
// Last block (r1-verified ticket tail) computes the loss -> no 3rd kernel.
__global__ __launch_bounds__(256, 4) void k_gemm(const bf16_t* __restrict__ hb,
                                                 float* __restrict__ Zrow,
                                                 const float* __restrict__ posPartial,
                                                 float* __restrict__ out,
                                                 unsigned* __restrict__ ticket) {
  // decode linear block id -> (bi <= bj) triangular pair
  const int t = blockIdx.x;
  int bj = (int)((sqrtf(8.0f * (float)t + 1.0f) - 1.0f) * 0.5f);
  while ((bj + 1) * (bj + 2) / 2 <= t) ++bj;
  while (bj * (bj + 1) / 2 > t) --bj;
  const int bi = t - bj * (bj + 1) / 2;
  const int rBase = bi * 128;
  const int cBase = bj * 128;
  const bool diag = (bi == bj);

  __shared__ __align__(16) bf16_t As[2][128][32];
  __shared__ __align__(16) bf16_t Bs[2][128][32];
  const int tid = threadIdx.x;
  const int lane = tid & 63;
  const int wave = tid >> 6;  // 0..3

  // staging: waves 0,1 -> As halves (64 rows each); waves 2,3 -> Bs halves.
  // One gl_lds16 issue covers 16 rows (lane -> row=lane>>2, chunk=lane&3).
  // Source chunk pre-swizzled with key (row>>1)&3 = (lane>>3)&3 (r9-verified:
  // 0 bank conflicts).
  const int half = wave & 1;
  const size_t stageRow = (size_t)((wave < 2 ? rBase : cBase) + half * 64);
  const int schunk = (lane & 3) ^ ((lane >> 3) & 3);
  const bf16_t* gsrc = hb + (stageRow + (lane >> 2)) * D_DIM + schunk * 8;
  bf16_t* lbase = (wave < 2) ? &As[0][half * 64][0] : &Bs[0][half * 64][0];

  // stage slab s (32 K-cols, 64 rows/wave) into buffer b: 4 x gl_lds16.
  auto STAGE = [&](int s, int b) {
#pragma unroll
    for (int i = 0; i < 4; ++i)
      gl_lds16(gsrc + (size_t)(i * 16) * D_DIM + s * 32,
               lbase + b * (128 * 32) + i * 16 * 32);
  };

  const int wm = wave >> 1, wn = wave & 1;
  const int quad = lane >> 4, l16 = lane & 15;
  // read-side un-swizzle: row = base16 + l16 -> key ((l16>>1)&3)
  const int cc = (quad ^ ((l16 >> 1) & 3)) * 8;

  f32x4 acc[4][4];
#pragma unroll
  for (int i = 0; i < 4; ++i)
#pragma unroll
    for (int j = 0; j < 4; ++j) acc[i][j] = (f32x4){0.f, 0.f, 0.f, 0.f};

  // prologue: slab 0 staged and visible
  STAGE(0, 0);
  asm volatile("s_waitcnt vmcnt(0)" ::: "memory");
  __builtin_amdgcn_s_barrier();

#pragma unroll
  for (int k = 0; k < 8; ++k) {
    const int b = k & 1;
    if (k + 1 < 8) STAGE(k + 1, b ^ 1);  // issue early; lands under compute

    bf16x8 af[4], bfr[4];
#pragma unroll
    for (int mt = 0; mt < 4; ++mt)
      af[mt] = *(const bf16x8*)&As[b][wm * 64 + mt * 16 + l16][cc];
#pragma unroll
    for (int nt = 0; nt < 4; ++nt)
      bfr[nt] = *(const bf16x8*)&Bs[b][wn * 64 + nt * 16 + l16][cc];
    asm volatile("s_waitcnt lgkmcnt(0)" ::: "memory");  // reads in registers
    __builtin_amdgcn_sched_barrier(0);                  // rule #18 fence

#pragma unroll
    for (int mt = 0; mt < 4; ++mt)
#pragma unroll
      for (int nt = 0; nt < 4; ++nt)
        acc[mt][nt] = __builtin_amdgcn_mfma_f32_16x16x32_bf16(
            af[mt], bfr[nt], acc[mt][nt], 0, 0, 0);

    if (k + 1 < 8) {
      asm volatile("s_waitcnt vmcnt(0)" ::: "memory");  // slab k+1 landed
      __builtin_amdgcn_s_barrier();  // single barrier: ready + WAR ordering
    }
  }

  // epilogue: e = exp(sim - SHIFT); row sums always, col sums for off-diag
  // (symmetry: entry (r,c) also stands in for (c,r)).
  const int rW = rBase + wm * 64 + quad * 4;
  const int cW = cBase + wn * 64 + l16;
  float colAcc[4] = {0.f, 0.f, 0.f, 0.f};
#pragma unroll
  for (int mt = 0; mt < 4; ++mt) {
#pragma unroll
    for (int rg = 0; rg < 4; ++rg) {
      const int rr = rW + mt * 16 + rg;
      float s = 0.f;
#pragma unroll
      for (int nt = 0; nt < 4; ++nt) {
        float e = __expf(acc[mt][nt][rg] - SHIFT);
        if (diag && (rr == cW + nt * 16)) e = 0.f;  // mask self-similarity
        s += e;
        colAcc[nt] += e;
      }
      s += __shfl_xor(s, 1);
      s += __shfl_xor(s, 2);
      s += __shfl_xor(s, 4);
      s += __shfl_xor(s, 8);
      if (l16 == 0) atomicAdd(&Zrow[rr], s);
    }
  }
  if (!diag) {
#pragma unroll
    for (int nt = 0; nt < 4; ++nt) {
      float c = colAcc[nt];
      c += __shfl_xor(c, 16);
      c += __shfl_xor(c, 32);
      if (lane < 16) atomicAdd(&Zrow[cW + nt * 16], c);
    }
  }

  // ---- fused finish (r1-verified ticket pattern): last block -> loss ----
  __shared__ float redL[4], redP[4];
  __shared__ int lastFlag;
  __syncthreads();  // drains each wave's vmcnt: this block's atomics done
  if (tid == 0) {
    __threadfence();
    lastFlag = (atomicAdd(ticket, 1u) == (unsigned)(NBLK - 1)) ? 1 : 0;
  }
  __syncthreads();
  if (lastFlag) {
    __threadfence();
    float sl = 0.f, sp = 0.f;
    for (int i = tid; i < N_TOT; i += 256) {
      float z = __hip_atomic_load(&Zrow[i], __ATOMIC_RELAXED,
                                  __HIP_MEMORY_SCOPE_AGENT);
      sl += __logf(z);
    }
    for (int i = tid; i < 1024; i += 256) sp += posPartial[i];
#pragma unroll
    for (int o = 32; o >= 1; o >>= 1) {
      sl += __shfl_xor(sl, o);
      sp += __shfl_xor(sp, o);
    }
    if (lane == 0) { redL[wave] = sl; redP[wave] = sp; }
    __syncthreads();
    if (tid == 0) {
      float L = redL[0] + redL[1] + redL[2] + redL[3];
      float P = redP[0] + redP[1] + redP[2] + redP[3];
      out[0] = L / (float)N_TOT + SHIFT - P / 2048.0f;
    }
  }
}

extern "C" void kernel_launch(void* const* d_in, const int* in_sizes, int n_in,
                              void* d_out, int out_size, void* d_ws, size_t ws_size,
                              hipStream_t stream) {
  const float* hi = (const float*)d_in[0];
  const float* hj = (const float*)d_in[1];
  float* out = (float*)d_out;

  bf16_t* hb = (bf16_t*)d_ws;                                        // 4 MB
  float* Zrow = (float*)((char*)d_ws + (size_t)N_TOT * D_DIM * 2);   // 32 KB
  float* posPartial = Zrow + N_TOT;                                  // 4 KB
  unsigned* ticket = (unsigned*)(posPartial + 1024);                 // 4 B

  k_prep<<<1024, 256, 0, stream>>>(hi, hj, hb, Zrow, posPartial, ticket);
  k_gemm<<<NBLK, 256, 0, stream>>>(hb, Zrow, posPartial, out, ticket);
}

// Round 13
// 95.025 us; speedup vs baseline: 3.9434x; 1.4914x over previous
//
#include <hip/hip_runtime.h>
#include <hip/hip_bf16.h>
#include <stdint.h>

#define BATCH 4096
#define N_TOT 8192
#define D_DIM 256
#define SHIFT 150.0f
#define SQRT2 1.41421356237309515f
#define NBLK 2080  // 64*65/2 triangular 128x128 tiles = 8 XCDs * 260

typedef __bf16 bf16_t;
typedef bf16_t bf16x8 __attribute__((ext_vector_type(8)));
typedef bf16_t bf16x4 __attribute__((ext_vector_type(4)));
typedef float f32x4 __attribute__((ext_vector_type(4)));

// global -> LDS direct copy, 16B per lane. LDS dest is wave-uniform base;
// HW scatters lane*16B linearly (cannot swizzle the dest -> swizzle the src).
__device__ __forceinline__ void gl_lds16(const void* g, void* l) {
  __builtin_amdgcn_global_load_lds(
      (const __attribute__((address_space(1))) void*)(uintptr_t)g,
      (__attribute__((address_space(3))) void*)(uint32_t)(uintptr_t)l,
      16, 0, 0);
}

// Fused: bf16 convert (x sqrt2), positive-pair dot partials, Zrow zero-init.
// 1024 blocks x 256 threads; wave w of block b owns row r = b*4+w.
__global__ void k_prep(const float* __restrict__ hi, const float* __restrict__ hj,
                       bf16_t* __restrict__ hb, float* __restrict__ Zrow,
                       float* __restrict__ posPartial) {
  const int wave = threadIdx.x >> 6, lane = threadIdx.x & 63;
  const int r = blockIdx.x * 4 + wave;
  const size_t off = (size_t)r * D_DIM + lane * 4;
  float4 a = *(const float4*)(hi + off);
  float4 b = *(const float4*)(hj + off);

  bf16x4 oa, ob;
  oa[0] = (bf16_t)(a.x * SQRT2); oa[1] = (bf16_t)(a.y * SQRT2);
  oa[2] = (bf16_t)(a.z * SQRT2); oa[3] = (bf16_t)(a.w * SQRT2);
  ob[0] = (bf16_t)(b.x * SQRT2); ob[1] = (bf16_t)(b.y * SQRT2);
  ob[2] = (bf16_t)(b.z * SQRT2); ob[3] = (bf16_t)(b.w * SQRT2);
  *(bf16x4*)(hb + off) = oa;
  *(bf16x4*)(hb + (size_t)BATCH * D_DIM + off) = ob;

  float d = a.x * b.x + a.y * b.y + a.z * b.z + a.w * b.w;
#pragma unroll
  for (int o = 32; o >= 1; o >>= 1) d += __shfl_xor(d, o);
  __shared__ float ps[4];
  if (lane == 0) ps[wave] = d;
  // zero 8 Zrow entries per block (8192 total over 1024 blocks)
  if (threadIdx.x < 8) Zrow[blockIdx.x * 8 + threadIdx.x] = 0.f;
  __syncthreads();
  if (threadIdx.x == 0) posPartial[blockIdx.x] = ps[0] + ps[1] + ps[2] + ps[3];
}

// Upper-triangular 128x128 tiles of sim = hb.hb^T; fused exp(sim-SHIFT) with
// row-sum AND (off-diag) col-sum accumulation into Zrow. 2080 blocks, 4 waves.
// r9 structure VERBATIM (best, 38.5us k_gemm): counted-vmcnt double-buffer +
// 4 blocks/CU. Per slab: STAGE(next, 4x gl_lds16) -> vmcnt(4) [slab k landed,
// issued a FULL ITERATION earlier -> ~zero wait; k+1 still in flight] ->
// s_barrier -> 8x ds_read_b128 -> lgkmcnt(0)+sched_barrier(0) [rule #18] ->
// 16 MFMA -> s_barrier [WAR]. No vmcnt(0) in the loop; never wait on a load
// younger than one slab of compute (r12 lesson).
// ONE change vs r9: XCD-chunked block swizzle (T1). FETCH_SIZE 16.5MB = 4x hb
// shows HBM refetch from cross-XCD L2 thrash; 2080 = 8*260 exactly ->
// bijective chunked remap localizes each XCD's bi/bj working set.
__global__ __launch_bounds__(256, 4) void k_gemm(const bf16_t* __restrict__ hb,
                                                 float* __restrict__ Zrow) {
  // XCD swizzle: consecutive hardware blocks round-robin XCDs; give XCD x the
  // contiguous triangular chunk [x*260, (x+1)*260).
  const int t0 = blockIdx.x;
  const int t = (t0 & 7) * (NBLK / 8) + (t0 >> 3);
  // decode linear block id -> (bi <= bj) triangular pair
  int bj = (int)((sqrtf(8.0f * (float)t + 1.0f) - 1.0f) * 0.5f);
  while ((bj + 1) * (bj + 2) / 2 <= t) ++bj;
  while (bj * (bj + 1) / 2 > t) --bj;
  const int bi = t - bj * (bj + 1) / 2;
  const int rBase = bi * 128;
  const int cBase = bj * 128;
  const bool diag = (bi == bj);

  __shared__ __align__(16) bf16_t As[2][128][32];
  __shared__ __align__(16) bf16_t Bs[2][128][32];
  const int tid = threadIdx.x;
  const int lane = tid & 63;
  const int wave = tid >> 6;  // 0..3

  // staging: waves 0,1 -> As halves (64 rows each); waves 2,3 -> Bs halves.
  // One gl_lds16 issue covers 16 rows (lane -> row=lane>>2, chunk=lane&3).
  // Source chunk pre-swizzled: (lane&3) ^ ((row>>1)&3) = (lane&3)^((lane>>3)&3)
  // (r9-verified: 0 bank conflicts).
  const int half = wave & 1;
  const size_t stageRow = (size_t)((wave < 2 ? rBase : cBase) + half * 64);
  const int schunk = (lane & 3) ^ ((lane >> 3) & 3);
  const bf16_t* gsrc = hb + (stageRow + (lane >> 2)) * D_DIM + schunk * 8;
  bf16_t* lbase = (wave < 2) ? &As[0][half * 64][0] : &Bs[0][half * 64][0];

  // stage slab s (32 K-cols, 64 rows/wave) into buffer b: 4 x gl_lds16.
  auto STAGE = [&](int s, int b) {
#pragma unroll
    for (int i = 0; i < 4; ++i)
      gl_lds16(gsrc + (size_t)(i * 16) * D_DIM + s * 32,
               lbase + b * (128 * 32) + i * 16 * 32);
  };

  const int wm = wave >> 1, wn = wave & 1;
  const int quad = lane >> 4, l16 = lane & 15;
  // read-side un-swizzle: row = ..+l16 -> key (l16>>1)&3 (bases mult. of 16)
  const int cc = (quad ^ ((l16 >> 1) & 3)) * 8;

  f32x4 acc[4][4];
#pragma unroll
  for (int i = 0; i < 4; ++i)
#pragma unroll
    for (int j = 0; j < 4; ++j) acc[i][j] = (f32x4){0.f, 0.f, 0.f, 0.f};

  STAGE(0, 0);  // prologue: slab 0 in flight

#pragma unroll
  for (int k = 0; k < 8; ++k) {
    const int b = k & 1;
    if (k + 1 < 8) {
      STAGE(k + 1, b ^ 1);  // next slab's loads fly across the barrier
      asm volatile("s_waitcnt vmcnt(4)" ::: "memory");  // slab k landed
    } else {
      asm volatile("s_waitcnt vmcnt(0)" ::: "memory");  // last slab: drain
    }
    __builtin_amdgcn_s_barrier();  // bar1: slab k fully visible in LDS

    bf16x8 af[4], bfr[4];
#pragma unroll
    for (int mt = 0; mt < 4; ++mt)
      af[mt] = *(const bf16x8*)&As[b][wm * 64 + mt * 16 + l16][cc];
#pragma unroll
    for (int nt = 0; nt < 4; ++nt)
      bfr[nt] = *(const bf16x8*)&Bs[b][wn * 64 + nt * 16 + l16][cc];
    asm volatile("s_waitcnt lgkmcnt(0)" ::: "memory");  // reads in registers
    __builtin_amdgcn_sched_barrier(0);                  // rule #18 fence

#pragma unroll
    for (int mt = 0; mt < 4; ++mt)
#pragma unroll
      for (int nt = 0; nt < 4; ++nt)
        acc[mt][nt] = __builtin_amdgcn_mfma_f32_16x16x32_bf16(
            af[mt], bfr[nt], acc[mt][nt], 0, 0, 0);

    __builtin_amdgcn_s_barrier();  // bar2: buffer b free for overwrite
  }

  // epilogue: e = exp(sim - SHIFT); row sums always, col sums for off-diag
  // (symmetry: entry (r,c) also stands in for (c,r)).
  const int rW = rBase + wm * 64 + quad * 4;
  const int cW = cBase + wn * 64 + l16;
  float colAcc[4] = {0.f, 0.f, 0.f, 0.f};
#pragma unroll
  for (int mt = 0; mt < 4; ++mt) {
#pragma unroll
    for (int rg = 0; rg < 4; ++rg) {
      const int rr = rW + mt * 16 + rg;
      float s = 0.f;
#pragma unroll
      for (int nt = 0; nt < 4; ++nt) {
        float e = __expf(acc[mt][nt][rg] - SHIFT);
        if (diag && (rr == cW + nt * 16)) e = 0.f;  // mask self-similarity
        s += e;
        colAcc[nt] += e;
      }
      s += __shfl_xor(s, 1);
      s += __shfl_xor(s, 2);
      s += __shfl_xor(s, 4);
      s += __shfl_xor(s, 8);
      if (l16 == 0) atomicAdd(&Zrow[rr], s);
    }
  }
  if (!diag) {
#pragma unroll
    for (int nt = 0; nt < 4; ++nt) {
      float c = colAcc[nt];
      c += __shfl_xor(c, 16);
      c += __shfl_xor(c, 32);
      if (lane < 16) atomicAdd(&Zrow[cW + nt * 16], c);
    }
  }
}

// One block: loss = mean(log Z + SHIFT) - sum(dot)/2048
__global__ void k_finish(const float* __restrict__ Zrow,
                         const float* __restrict__ posPartial,
                         float* __restrict__ out) {
  const int t = threadIdx.x;  // 0..1023
  float4 z0 = *(const float4*)(Zrow + t * 8);
  float4 z1 = *(const float4*)(Zrow + t * 8 + 4);
  float sl = __logf(z0.x) + __logf(z0.y) + __logf(z0.z) + __logf(z0.w) +
             __logf(z1.x) + __logf(z1.y) + __logf(z1.z) + __logf(z1.w);
  float sp = posPartial[t];
#pragma unroll
  for (int o = 32; o >= 1; o >>= 1) {
    sl += __shfl_xor(sl, o);
    sp += __shfl_xor(sp, o);
  }
  __shared__ float pl[16], pp[16];
  const int wave = t >> 6, lane = t & 63;
  if (lane == 0) { pl[wave] = sl; pp[wave] = sp; }
  __syncthreads();
  if (t == 0) {
    float L = 0.f, P = 0.f;
    for (int i = 0; i < 16; ++i) { L += pl[i]; P += pp[i]; }
    out[0] = L / (float)N_TOT + SHIFT - P / 2048.0f;
  }
}

extern "C" void kernel_launch(void* const* d_in, const int* in_sizes, int n_in,
                              void* d_out, int out_size, void* d_ws, size_t ws_size,
                              hipStream_t stream) {
  const float* hi = (const float*)d_in[0];
  const float* hj = (const float*)d_in[1];
  float* out = (float*)d_out;

  bf16_t* hb = (bf16_t*)d_ws;                                        // 4 MB
  float* Zrow = (float*)((char*)d_ws + (size_t)N_TOT * D_DIM * 2);   // 32 KB
  float* posPartial = Zrow + N_TOT;                                  // 4 KB

  k_prep<<<1024, 256, 0, stream>>>(hi, hj, hb, Zrow, posPartial);
  k_gemm<<<NBLK, 256, 0, stream>>>(hb, Zrow);
  k_finish<<<1, 1024, 0, stream>>>(Zrow, posPartial, out);
}